// Round 14
// baseline (643.448 us; speedup 1.0000x reference)
//
#include <hip/hip_runtime.h>
#include <math.h>

#define NYg 1024
#define NXg 1024
#define W   1024
#define NSTEPS 64
#define NBLK 512
#define EN (NBLK * W)

// ---- ctrl (dword offsets in d_ws) ----
// slotsf[s*512 + b], s=0..NSTEPS (65*512 = 33280 dwords): per-block max-D,
//   plain system store, value-as-flag (nonzero == published). Seeded EPS at s=0.
// nbf[b*32] at dword WS_NBF (512 flags): neighbor progress (R4 protocol).
#define WS_NBF   33280
#define WS_CTRL_END 49664
#define WS_GRIDS 65536                     // float offset where exchange arrays begin

constexpr float DXf   = 50.0f;
constexpr float DYf   = 50.0f;
constexpr float TTOTf = 32.0f;
constexpr float DTMAXf= 0.5f;
constexpr float EPSf  = 1e-10f;
constexpr float TFREQ = 5.0f;
constexpr float LAPSE = 0.0065f;
constexpr float MELTF = 0.5f;
constexpr double RHOG = 910.0 * 9.81;
constexpr float  CDf  = (float)(1e-17 * RHOG * RHOG * RHOG);

// memory-side (coherence-point) accessors — bypass non-coherent per-XCD L2s
__device__ __forceinline__ float scloadf(const float* p) {
    return __hip_atomic_load(p, __ATOMIC_RELAXED, __HIP_MEMORY_SCOPE_SYSTEM);
}
__device__ __forceinline__ void scstoref(float* p, float v) {
    __hip_atomic_store(p, v, __ATOMIC_RELAXED, __HIP_MEMORY_SCOPE_SYSTEM);
}
__device__ __forceinline__ unsigned scloadu(const unsigned* p) {
    return __hip_atomic_load(p, __ATOMIC_RELAXED, __HIP_MEMORY_SCOPE_SYSTEM);
}

// diffusivity on one staggered cell — expression verbatim (bit-exact)
__device__ __forceinline__ float dfunc(float h00, float h01, float h10, float h11,
                                       float z00, float z01, float z10, float z11)
{
    float havg = 0.25f * (h00 + h11 + h01 + h10);
    float sx = ((z01 - z00) + (z11 - z10)) * (0.5f / DXf);
    float sy = ((z10 - z00) + (z11 - z01)) * (0.5f / DYf);
    float sn = sqrtf(sx * sx + sy * sy + EPSf);
    float h2 = havg * havg;
    float h4 = h2 * h2;
    return CDf * (h4 * havg) * (sn * sn) + EPSf;
}

// ---------------- init: zero ctrl, seed step-0 slots with EPS ----
__global__ __launch_bounds__(256) void k_init(unsigned* __restrict__ ctrl)
{
    int idx = blockIdx.x * blockDim.x + threadIdx.x;
    int stride = gridDim.x * blockDim.x;
    for (int i = idx; i < WS_CTRL_END; i += stride) {
        unsigned v = 0u;
        if (i < NBLK) v = __float_as_uint(EPSf);   // slotsf[0*512 + b] = EPS
        ctrl[i] = v;
    }
}

// ---------------- persistent kernel: 2-rows/block, 2 blocks/CU ----------------
// R4 protocol verbatim; geometry halved for TLP: 512 blocks x 1024 threads =
// 32/32 waves per CU (was 16/32). When one block stalls on an RT, the
// co-resident block computes — the sync floor hides under compute.
// Block b owns rows r0=2b, r0+1 (+1 redundant row r0+2).
//   LDS: sZ[3][W] z rows r0..r0+2 ; sH[3][W] ; sD[2][W] stag rows r0..r0+1.
//   Regs: z_[5] rows r0-1..r0+3 ; h_[3] ; dreg[2] ; dtop/dtopL (stag r0-1),
//         dbot/dbotL (stag r0+2).
// Exchange per block: ONE z row (r0+1 — serves BOTH neighbors), D stag r0
// (down), D stag r0+1 (up). dt bit-exact: same D set, max partition-invariant.
__global__ __launch_bounds__(1024, 8) void k_run(
    float* __restrict__ EZ0,  float* __restrict__ EZ1,
    float* __restrict__ EDd0, float* __restrict__ EDd1,
    float* __restrict__ EDu0, float* __restrict__ EDu1,
    const float* __restrict__ ztopo, const float* __restrict__ precip,
    const float* __restrict__ mask, const float* __restrict__ tma,
    const float* __restrict__ tmj, unsigned* __restrict__ ctrl,
    float* __restrict__ Hout)
{
    __shared__ float sZ[3][W];
    __shared__ float sH[3][W];
    __shared__ float sD[2][W];
    __shared__ float smax16[16];
    __shared__ float smax8[8];

    float*    slotsf = (float*)ctrl;
    unsigned* nbf    = ctrl + WS_NBF;

    const int c   = threadIdx.x;          // column 0..1023
    const int b   = blockIdx.x;           // owns rows 2b..2b+1 (+1 redundant)
    const int r0  = b * 2;
    const int lane = c & 63, wid = c >> 6;
    const bool hasA = (b > 0), hasB = (b < NBLK - 1);
    const bool cL = (c >= 1), cR = (c <= NXg - 2);
    const int cm = (c == 0) ? 0 : c - 1;          // clamped (guard via iv)
    const int cp = (c == W - 1) ? W - 1 : c + 1;

    const float TMA = tma[0], TMJ = tmj[0];

    // register-carried own-column state
    float z_[5];                  // z rows r0-1 .. r0+3
    float h_[3];                  // h rows r0 .. r0+2
    float dreg[2];                // D stag rows r0..r0+1, col c
    float dtop, dtopL;            // D stag row r0-1, cols c / c-1
    float dbot, dbotL;            // D stag row r0+2, cols c / c-1
    float smbr[3], ztr[3];

    // ---- pre-loop: state(0) ----
    #pragma unroll
    for (int q = 0; q < 5; ++q) {
        int r = r0 - 1 + q;
        z_[q] = (r >= 0 && r < NYg) ? ztopo[r * W + c] : 0.0f;
    }
    #pragma unroll
    for (int rr = 0; rr < 3; ++rr) {
        int r = r0 + rr;
        h_[rr] = 0.0f;
        if (r < NYg) {
            float z = z_[rr + 1];
            ztr[rr] = z;
            float t_ma = TMA - LAPSE * z;
            float t_mj = TMJ - LAPSE * z;
            float acc  = (t_ma < 0.0f) ? precip[r * W + c] : 0.0f;
            float abl  = MELTF * fmaxf(t_mj, 0.0f);
            smbr[rr] = (acc - abl) * mask[r * W + c];
            sZ[rr][c] = z;
            sH[rr][c] = 0.0f;
        } else {
            ztr[rr] = 0.0f; smbr[rr] = 0.0f;
            sZ[rr][c] = 0.0f;
            sH[rr][c] = 0.0f;
        }
    }
    dtop = EPSf; dtopL = EPSf; dbot = EPSf; dbotL = EPSf;
    #pragma unroll
    for (int q = 0; q < 2; ++q) { dreg[q] = EPSf; sD[q][c] = EPSf; }
    __syncthreads();

    float t = 0.0f, tl = 0.0f;

    for (int s = 0; s < NSTEPS; ++s) {
        const float* EZr  = (s & 1) ? EZ1  : EZ0;   // z row r0+1 exports (state s)
        float*       EZw  = (s & 1) ? EZ0  : EZ1;
        const float* EDdr = (s & 1) ? EDd1 : EDd0;  // D stag r0 exports (down)
        float*       EDdw = (s & 1) ? EDd0 : EDd1;
        const float* EDur = (s & 1) ? EDu1 : EDu0;  // D stag r0+1 exports (up)
        float*       EDuw = (s & 1) ? EDu0 : EDu1;

        // ---- A: per-thread neighbor-flag poll + halo import (no barrier) ----
        if (s > 0) {
            if (hasA)
                while (scloadu(&nbf[(b - 1) * 32]) < (unsigned)s) __builtin_amdgcn_s_sleep(1);
            if (hasB)
                while (scloadu(&nbf[(b + 1) * 32]) < (unsigned)s) __builtin_amdgcn_s_sleep(1);
            if (hasA) {
                z_[0] = scloadf(EZr + (b - 1) * W + c);              // z row r0-1
                if (cR) dtop  = scloadf(EDur + (b - 1) * W + c);     // stag r0-1 @ c
                if (cL) dtopL = scloadf(EDur + (b - 1) * W + (c-1)); // stag r0-1 @ c-1
            }
            if (hasB) {
                z_[4] = scloadf(EZr + (b + 1) * W + c);              // z row r0+3
                if (cR) dbot  = scloadf(EDdr + (b + 1) * W + c);     // stag r0+2 @ c
                if (cL) dbotL = scloadf(EDdr + (b + 1) * W + (c-1)); // stag r0+2 @ c-1
            }
        }

        // ---- C1: dHdt (dt-independent). Shared qy interfaces (bit-exact) ----
        float dl[4], doa[4];
        dl[0] = dtopL;      doa[0] = dtop;
        dl[1] = sD[0][cm];  doa[1] = dreg[0];
        dl[2] = sD[1][cm];  doa[2] = dreg[1];
        dl[3] = dbotL;      doa[3] = dbot;

        float zl[3], zr[3];
        #pragma unroll
        for (int q = 0; q < 3; ++q) { zl[q] = sZ[q][cm]; zr[q] = sZ[q][cp]; }

        // vertical flux interface k: qyT(rr)=qy[rr], qyB(rr)=qy[rr+1]
        float qy[4];
        #pragma unroll
        for (int k = 0; k < 4; ++k)
            qy[k] = -0.5f * (dl[k] + doa[k]) * (z_[k + 1] - z_[k]) * (1.0f / DYf);

        float dh[3];
        bool  inter[3];
        #pragma unroll
        for (int rr = 0; rr < 3; ++rr) {
            int r = r0 + rr;
            bool iv = (r >= 1 && r <= NYg - 2 && cL && cR);
            float zc  = z_[rr + 1];
            float qxR = -0.5f * (doa[rr] + doa[rr + 1]) * (zr[rr] - zc) * (1.0f / DXf);
            float qxL = -0.5f * (dl[rr]  + dl[rr + 1])  * (zc - zl[rr]) * (1.0f / DXf);
            float d = -((qxR - qxL) * (1.0f / DXf) + (qy[rr + 1] - qy[rr]) * (1.0f / DYf));
            dh[rr] = iv ? d : 0.0f;
            inter[rr] = iv;
        }

        // ---- W: lanes 0..511 poll per-block slots (value==flag), reduce ----
        if (c < NBLK) {
            const float* sl = slotsf + s * NBLK + c;
            float v = scloadf(sl);
            while (__float_as_uint(v) == 0u) { __builtin_amdgcn_s_sleep(1); v = scloadf(sl); }
            #pragma unroll
            for (int off = 32; off >= 1; off >>= 1)
                v = fmaxf(v, __shfl_xor(v, off, 64));
            if (lane == 0) smax8[wid] = v;           // wid 0..7
        }
        __syncthreads();   // smax8 visible; also: C1 LDS reads done before C2 writes

        float mD = fmaxf(fmaxf(fmaxf(smax8[0], smax8[1]), fmaxf(smax8[2], smax8[3])),
                         fmaxf(fmaxf(smax8[4], smax8[5]), fmaxf(smax8[6], smax8[7])));
        float dt = fminf(2500.0f / (2.7f * mD), DTMAXf);
        if (!(t < TTOTf)) dt = 0.0f;
        float nt  = t + dt;
        bool  upd = (nt - tl) >= TFREQ;

        // ---- C2+E: finalize h/z in regs, write b32 LDS, export, smb refresh ----
        #pragma unroll
        for (int rr = 0; rr < 3; ++rr) {
            int r = r0 + rr;
            if (r < NYg) {
                float h, z;
                if (inter[rr]) { h = fmaxf(h_[rr] + dt * (dh[rr] + smbr[rr]), 0.0f);
                                 z = ztr[rr] + h; }
                else           { h = 0.0f; z = z_[rr + 1]; }
                h_[rr] = h; z_[rr + 1] = z;
                sZ[rr][c] = z;
                sH[rr][c] = h;
                if (rr == 1) scstoref(EZw + b * W + c, z);   // row r0+1 serves BOTH neighbors
                if (upd) {
                    float t_ma = TMA - LAPSE * z;
                    float t_mj = TMJ - LAPSE * z;
                    float acc  = (t_ma < 0.0f) ? precip[r * W + c] : 0.0f;
                    float abl  = MELTF * fmaxf(t_mj, 0.0f);
                    smbr[rr] = (acc - abl) * mask[r * W + c];
                }
            } else {
                h_[rr] = 0.0f;
            }
        }
        __syncthreads();   // (z,h) writeback visible for G

        // ---- G: D(s+1); slot publish BEFORE export drain; then nbf ----
        if (s < NSTEPS - 1) {
            float m = 0.0f;
            float dv0 = 0.0f, dv1 = 0.0f;
            if (cR) {                                   // stag r0 (row-valid always)
                dv0 = dfunc(h_[0], sH[0][c + 1], h_[1], sH[1][c + 1],
                            z_[1], sZ[0][c + 1], z_[2], sZ[1][c + 1]);
                m = fmaxf(m, dv0);
                if (hasA) scstoref(EDdw + b * W + c, dv0);
            }
            if (r0 + 1 <= NYg - 2 && cR) {              // stag r0+1
                dv1 = dfunc(h_[1], sH[1][c + 1], h_[2], sH[2][c + 1],
                            z_[2], sZ[1][c + 1], z_[3], sZ[2][c + 1]);
                m = fmaxf(m, dv1);
                if (hasB) scstoref(EDuw + b * W + c, dv1);
            }
            sD[0][c] = dv0;
            sD[1][c] = dv1;
            dreg[0] = dv0; dreg[1] = dv1;
            #pragma unroll
            for (int off = 32; off >= 1; off >>= 1)
                m = fmaxf(m, __shfl_xor(m, off, 64));
            if (lane == 0) smax16[wid] = m;
            __syncthreads();                         // smax16 (and sD) visible
            if (c == 0) {
                // global-dt chain: publish block max NOW (plain store, no drain)
                #pragma unroll
                for (int q = 1; q < 16; ++q) m = fmaxf(m, smax16[q]);
                scstoref(slotsf + (s + 1) * NBLK + b, m);
            }
            asm volatile("s_waitcnt vmcnt(0)" ::: "memory");  // own exports drained
            __syncthreads();                                   // ALL exports drained
            if (c == 0)
                __hip_atomic_store(&nbf[b * 32], (unsigned)(s + 1),
                                   __ATOMIC_RELAXED, __HIP_MEMORY_SCOPE_SYSTEM);
        }

        t = nt;
        if (upd) tl = nt;
    }

    // ---- final: H(64) own rows -> d_out ----
    #pragma unroll
    for (int rr = 0; rr < 2; ++rr)
        Hout[(r0 + rr) * W + c] = h_[rr];
}

extern "C" void kernel_launch(void* const* d_in, const int* in_sizes, int n_in,
                              void* d_out, int out_size, void* d_ws, size_t ws_size,
                              hipStream_t stream)
{
    const float* precip = (const float*)d_in[0];
    const float* tma    = (const float*)d_in[1];
    const float* tmj    = (const float*)d_in[2];
    const float* ztopo  = (const float*)d_in[3];
    const float* mask   = (const float*)d_in[4];

    unsigned* ctrl = (unsigned*)d_ws;
    float* g = (float*)d_ws + WS_GRIDS;
    float* EZ0  = g + 0 * EN; float* EZ1  = g + 1 * EN;
    float* EDd0 = g + 2 * EN; float* EDd1 = g + 3 * EN;
    float* EDu0 = g + 4 * EN; float* EDu1 = g + 5 * EN;

    k_init<<<dim3(64), dim3(256), 0, stream>>>(ctrl);

    k_run<<<dim3(512), dim3(1024), 0, stream>>>(EZ0, EZ1, EDd0, EDd1, EDu0, EDu1,
                                                ztopo, precip, mask, tma, tmj,
                                                ctrl, (float*)d_out);
}

// Round 15
// 390.970 us; speedup vs baseline: 1.6458x; 1.6458x over previous
//
#include <hip/hip_runtime.h>
#include <math.h>

#define NYg 1024
#define NXg 1024
#define W   1024
#define NSTEPS 64
#define NBLK 256
#define EN (NBLK * W)

// ---- ctrl (dword offsets in d_ws) ----
// slotsf[s*256 + b], s=0..NSTEPS: per-block max-D for step s. Written once per
// step with a plain system store; nonzero bit pattern == "published" (every
// block max >= EPS > 0). Seeded EPSf at s=0 by k_init (D(0)==EPS everywhere).
// nbf[b*32] at dword WS_NBF: neighbor progress flags.
#define WS_SLOTS 0
#define WS_NBF   24576
#define WS_CTRL_END 32768
#define WS_GRIDS 32768                     // float offset where exchange arrays begin

constexpr float DXf   = 50.0f;
constexpr float DYf   = 50.0f;
constexpr float TTOTf = 32.0f;
constexpr float DTMAXf= 0.5f;
constexpr float EPSf  = 1e-10f;
constexpr float TFREQ = 5.0f;
constexpr float LAPSE = 0.0065f;
constexpr float MELTF = 0.5f;
constexpr double RHOG = 910.0 * 9.81;
constexpr float  CDf  = (float)(1e-17 * RHOG * RHOG * RHOG);

// memory-side (coherence-point) accessors — bypass non-coherent per-XCD L2s
__device__ __forceinline__ float scloadf(const float* p) {
    return __hip_atomic_load(p, __ATOMIC_RELAXED, __HIP_MEMORY_SCOPE_SYSTEM);
}
__device__ __forceinline__ void scstoref(float* p, float v) {
    __hip_atomic_store(p, v, __ATOMIC_RELAXED, __HIP_MEMORY_SCOPE_SYSTEM);
}
__device__ __forceinline__ unsigned scloadu(const unsigned* p) {
    return __hip_atomic_load(p, __ATOMIC_RELAXED, __HIP_MEMORY_SCOPE_SYSTEM);
}

// diffusivity on one staggered cell — expression verbatim (bit-exact)
__device__ __forceinline__ float dfunc(float h00, float h01, float h10, float h11,
                                       float z00, float z01, float z10, float z11)
{
    float havg = 0.25f * (h00 + h11 + h01 + h10);
    float sx = ((z01 - z00) + (z11 - z10)) * (0.5f / DXf);
    float sy = ((z10 - z00) + (z11 - z01)) * (0.5f / DYf);
    float sn = sqrtf(sx * sx + sy * sy + EPSf);
    float h2 = havg * havg;
    float h4 = h2 * h2;
    return CDf * (h4 * havg) * (sn * sn) + EPSf;
}

// ---------------- init: zero ctrl, seed step-0 slots with EPS ----
__global__ __launch_bounds__(256) void k_init(unsigned* __restrict__ ctrl)
{
    int idx = blockIdx.x * blockDim.x + threadIdx.x;
    int stride = gridDim.x * blockDim.x;
    for (int i = idx; i < WS_CTRL_END; i += stride) {
        unsigned v = 0u;
        if (i < NBLK) v = __float_as_uint(EPSf);   // slotsf[0*256 + b] = EPS
        ctrl[i] = v;
    }
}

// ---------------- persistent kernel (R4, verified 340-348us / absmax 0.0, x4) ---------
// Conflict-free scalar b32 LDS (cross-lane slices only):
//   sZ[5][W] z rows r0..r0+4 ; sH[5][W] h rows ; sD[4][W] D stag rows r0..r0+3.
// Registers carry all own-column state incl. the 4 D-halo values.
// Sync protocol:
//   - per-block slot publish: ONE plain system store of the block max, value
//     doubles as the "published" flag (nonzero). No fetch_max / fetch_add.
//   - slot published BEFORE the export drain (needs only the smax16 barrier);
//     nbf published after vmcnt(0)+barrier (gates EZ/ED halo buffers).
//   - A-phase: every thread polls both neighbor flags itself (wave-uniform
//     loads), so A needs no barrier; halo loads are self-ordered per thread.
// Session conclusion (R5-R13, each a controlled single-change probe):
//   flag/data fusion, waiter topology, flag timing, barrier elision, dt
//   speculation, hand-pipelining, and 2x occupancy ALL regress or are neutral.
//   The kernel is sync-structure-bound: 64 serialized grid-wide dt reductions
//   x (~2.9us issue + ~2.4us correlated RT/barrier floor). This structure is
//   the measured local optimum.
__global__ __launch_bounds__(1024, 1) void k_run(
    float* __restrict__ EZa0, float* __restrict__ EZa1,
    float* __restrict__ EZb0, float* __restrict__ EZb1,
    float* __restrict__ EDa0, float* __restrict__ EDa1,
    float* __restrict__ EDb0, float* __restrict__ EDb1,
    const float* __restrict__ ztopo, const float* __restrict__ precip,
    const float* __restrict__ mask, const float* __restrict__ tma,
    const float* __restrict__ tmj, unsigned* __restrict__ ctrl,
    float* __restrict__ Hout)
{
    __shared__ float sZ[5][W];
    __shared__ float sH[5][W];
    __shared__ float sD[4][W];
    __shared__ float smax16[16];
    __shared__ float smax4[4];

    float*    slotsf = (float*)ctrl;
    unsigned* nbf    = ctrl + WS_NBF;

    const int c   = threadIdx.x;          // column 0..1023
    const int b   = blockIdx.x;           // owns rows 4b..4b+3 (+1 redundant)
    const int r0  = b * 4;
    const int lane = c & 63, wid = c >> 6;
    const bool hasA = (b > 0), hasB = (b < NBLK - 1);
    const bool cL = (c >= 1), cR = (c <= NXg - 2);
    const int cm = (c == 0) ? 0 : c - 1;          // clamped (guard via iv)
    const int cp = (c == W - 1) ? W - 1 : c + 1;

    const float TMA = tma[0], TMJ = tmj[0];

    // register-carried own-column state
    float z_[7];                  // z rows r0-1 .. r0+5
    float h_[5];                  // h rows r0 .. r0+4
    float dreg[4];                // D stag rows r0..r0+3, col c
    float dtop, dtopL;            // D stag row r0-1, cols c / c-1
    float dbot, dbotL;            // D stag row r0+4, cols c / c-1
    float smbr[5], ztr[5];

    // ---- pre-loop: state(0) ----
    #pragma unroll
    for (int q = 0; q < 7; ++q) {
        int r = r0 - 1 + q;
        z_[q] = (r >= 0 && r < NYg) ? ztopo[r * W + c] : 0.0f;
    }
    #pragma unroll
    for (int rr = 0; rr < 5; ++rr) {
        int r = r0 + rr;
        h_[rr] = 0.0f;
        if (r < NYg) {
            float z = z_[rr + 1];
            ztr[rr] = z;
            float t_ma = TMA - LAPSE * z;
            float t_mj = TMJ - LAPSE * z;
            float acc  = (t_ma < 0.0f) ? precip[r * W + c] : 0.0f;
            float abl  = MELTF * fmaxf(t_mj, 0.0f);
            smbr[rr] = (acc - abl) * mask[r * W + c];
            sZ[rr][c] = z;
            sH[rr][c] = 0.0f;
        } else {
            ztr[rr] = 0.0f; smbr[rr] = 0.0f;
            sZ[rr][c] = 0.0f;
            sH[rr][c] = 0.0f;
        }
    }
    dtop = EPSf; dtopL = EPSf; dbot = EPSf; dbotL = EPSf;
    #pragma unroll
    for (int q = 0; q < 4; ++q) { dreg[q] = EPSf; sD[q][c] = EPSf; }
    __syncthreads();

    float t = 0.0f, tl = 0.0f;

    for (int s = 0; s < NSTEPS; ++s) {
        const float* EZar = (s & 1) ? EZa1 : EZa0;   // z row r0+1 exports (state s)
        float*       EZaw = (s & 1) ? EZa0 : EZa1;
        const float* EZbr = (s & 1) ? EZb1 : EZb0;   // z row r0+3 exports
        float*       EZbw = (s & 1) ? EZb0 : EZb1;
        const float* EDar = (s & 1) ? EDa1 : EDa0;   // D stag row r0 exports
        float*       EDaw = (s & 1) ? EDa0 : EDa1;
        const float* EDbr = (s & 1) ? EDb1 : EDb0;   // D stag row r0+3 exports
        float*       EDbw = (s & 1) ? EDb0 : EDb1;

        // ---- A: per-thread neighbor-flag poll + halo import (no barrier) ----
        if (s > 0) {
            if (hasA)
                while (scloadu(&nbf[(b - 1) * 32]) < (unsigned)s) __builtin_amdgcn_s_sleep(1);
            if (hasB)
                while (scloadu(&nbf[(b + 1) * 32]) < (unsigned)s) __builtin_amdgcn_s_sleep(1);
            if (hasA) {
                z_[0] = scloadf(EZbr + (b - 1) * W + c);            // z row r0-1
                if (cR) dtop  = scloadf(EDbr + (b - 1) * W + c);    // D stag r0-1 @ c
                if (cL) dtopL = scloadf(EDbr + (b - 1) * W + (c-1));// D stag r0-1 @ c-1
            }
            if (hasB) {
                z_[6] = scloadf(EZar + (b + 1) * W + c);            // z row r0+5
                if (cR) dbot  = scloadf(EDar + (b + 1) * W + c);    // D stag r0+4 @ c
                if (cL) dbotL = scloadf(EDar + (b + 1) * W + (c-1));// D stag r0+4 @ c-1
            }
        }

        // ---- C1: dHdt (dt-independent). Shared qy interfaces (bit-exact) ----
        float dl[6], doa[6];
        dl[0] = dtopL;      doa[0] = dtop;
        dl[1] = sD[0][cm];  doa[1] = dreg[0];
        dl[2] = sD[1][cm];  doa[2] = dreg[1];
        dl[3] = sD[2][cm];  doa[3] = dreg[2];
        dl[4] = sD[3][cm];  doa[4] = dreg[3];
        dl[5] = dbotL;      doa[5] = dbot;

        float zl[5], zr[5];
        #pragma unroll
        for (int q = 0; q < 5; ++q) { zl[q] = sZ[q][cm]; zr[q] = sZ[q][cp]; }

        // vertical flux interface k: qyT(rr)=qy[rr], qyB(rr)=qy[rr+1]
        float qy[6];
        #pragma unroll
        for (int k = 0; k < 6; ++k)
            qy[k] = -0.5f * (dl[k] + doa[k]) * (z_[k + 1] - z_[k]) * (1.0f / DYf);

        float dh[5];
        bool  inter[5];
        #pragma unroll
        for (int rr = 0; rr < 5; ++rr) {
            int r = r0 + rr;
            bool iv = (r >= 1 && r <= NYg - 2 && cL && cR);
            float zc  = z_[rr + 1];
            float qxR = -0.5f * (doa[rr] + doa[rr + 1]) * (zr[rr] - zc) * (1.0f / DXf);
            float qxL = -0.5f * (dl[rr]  + dl[rr + 1])  * (zc - zl[rr]) * (1.0f / DXf);
            float d = -((qxR - qxL) * (1.0f / DXf) + (qy[rr + 1] - qy[rr]) * (1.0f / DYf));
            dh[rr] = iv ? d : 0.0f;
            inter[rr] = iv;
        }

        // ---- W: lanes 0..255 poll per-block slots (value==flag), reduce ----
        if (c < NBLK) {
            const float* sl = slotsf + s * NBLK + c;
            float v = scloadf(sl);
            while (__float_as_uint(v) == 0u) { __builtin_amdgcn_s_sleep(1); v = scloadf(sl); }
            #pragma unroll
            for (int off = 32; off >= 1; off >>= 1)
                v = fmaxf(v, __shfl_xor(v, off, 64));
            if (lane == 0) smax4[wid] = v;
        }
        __syncthreads();   // smax4 visible; also: C1 LDS reads done before C2 writes

        float mD = fmaxf(fmaxf(smax4[0], smax4[1]), fmaxf(smax4[2], smax4[3]));
        float dt = fminf(2500.0f / (2.7f * mD), DTMAXf);
        if (!(t < TTOTf)) dt = 0.0f;
        float nt  = t + dt;
        bool  upd = (nt - tl) >= TFREQ;

        // ---- C2+E: finalize h/z in regs, write b32 LDS, export, smb refresh ----
        #pragma unroll
        for (int rr = 0; rr < 5; ++rr) {
            int r = r0 + rr;
            if (r < NYg) {
                float h, z;
                if (inter[rr]) { h = fmaxf(h_[rr] + dt * (dh[rr] + smbr[rr]), 0.0f);
                                 z = ztr[rr] + h; }
                else           { h = 0.0f; z = z_[rr + 1]; }
                h_[rr] = h; z_[rr + 1] = z;
                sZ[rr][c] = z;
                sH[rr][c] = h;
                if (rr == 1 && hasA) scstoref(EZaw + b * W + c, z);
                if (rr == 3 && hasB) scstoref(EZbw + b * W + c, z);
                if (upd) {
                    float t_ma = TMA - LAPSE * z;
                    float t_mj = TMJ - LAPSE * z;
                    float acc  = (t_ma < 0.0f) ? precip[r * W + c] : 0.0f;
                    float abl  = MELTF * fmaxf(t_mj, 0.0f);
                    smbr[rr] = (acc - abl) * mask[r * W + c];
                }
            } else {
                h_[rr] = 0.0f;
            }
        }
        __syncthreads();   // (z,h) writeback visible for G

        // ---- G: D(s+1); slot publish BEFORE export drain; then nbf ----
        if (s < NSTEPS - 1) {
            float m = 0.0f;
            float dv[4];
            #pragma unroll
            for (int rr = 0; rr < 4; ++rr) {
                int i = r0 + rr;
                float dd = 0.0f;
                if (i <= NYg - 2 && cR) {
                    dd = dfunc(h_[rr], sH[rr][c + 1],
                               h_[rr + 1], sH[rr + 1][c + 1],
                               z_[rr + 1], sZ[rr][c + 1],
                               z_[rr + 2], sZ[rr + 1][c + 1]);
                    m = fmaxf(m, dd);
                    if (rr == 0 && hasA) scstoref(EDaw + b * W + c, dd);
                    if (rr == 3 && hasB) scstoref(EDbw + b * W + c, dd);
                }
                dv[rr] = dd;
            }
            sD[0][c] = dv[0];
            sD[1][c] = dv[1];
            sD[2][c] = dv[2];
            sD[3][c] = dv[3];
            dreg[0] = dv[0]; dreg[1] = dv[1]; dreg[2] = dv[2]; dreg[3] = dv[3];
            #pragma unroll
            for (int off = 32; off >= 1; off >>= 1)
                m = fmaxf(m, __shfl_xor(m, off, 64));
            if (lane == 0) smax16[wid] = m;
            __syncthreads();                         // smax16 (and sD) visible
            if (c == 0) {
                // global-dt chain: publish block max NOW (plain store, no drain)
                #pragma unroll
                for (int q = 1; q < 16; ++q) m = fmaxf(m, smax16[q]);
                scstoref(slotsf + (s + 1) * NBLK + b, m);
            }
            asm volatile("s_waitcnt vmcnt(0)" ::: "memory");  // own exports drained
            __syncthreads();                                   // ALL exports drained
            if (c == 0)
                __hip_atomic_store(&nbf[b * 32], (unsigned)(s + 1),
                                   __ATOMIC_RELAXED, __HIP_MEMORY_SCOPE_SYSTEM);
        }

        t = nt;
        if (upd) tl = nt;
    }

    // ---- final: H(64) own rows -> d_out ----
    #pragma unroll
    for (int rr = 0; rr < 4; ++rr)
        Hout[(r0 + rr) * W + c] = h_[rr];
}

extern "C" void kernel_launch(void* const* d_in, const int* in_sizes, int n_in,
                              void* d_out, int out_size, void* d_ws, size_t ws_size,
                              hipStream_t stream)
{
    const float* precip = (const float*)d_in[0];
    const float* tma    = (const float*)d_in[1];
    const float* tmj    = (const float*)d_in[2];
    const float* ztopo  = (const float*)d_in[3];
    const float* mask   = (const float*)d_in[4];

    unsigned* ctrl = (unsigned*)d_ws;
    float* g = (float*)d_ws + WS_GRIDS;
    float* EZa0 = g + 0 * EN; float* EZa1 = g + 1 * EN;
    float* EZb0 = g + 2 * EN; float* EZb1 = g + 3 * EN;
    float* EDa0 = g + 4 * EN; float* EDa1 = g + 5 * EN;
    float* EDb0 = g + 6 * EN; float* EDb1 = g + 7 * EN;

    k_init<<<dim3(64), dim3(256), 0, stream>>>(ctrl);

    k_run<<<dim3(256), dim3(1024), 0, stream>>>(EZa0, EZa1, EZb0, EZb1,
                                                EDa0, EDa1, EDb0, EDb1,
                                                ztopo, precip, mask, tma, tmj,
                                                ctrl, (float*)d_out);
}